// Round 1
// baseline (542910.645 us; speedup 1.0000x reference)
//
#include <hip/hip_runtime.h>
#include <hip/hip_bf16.h>

// ---------------------------------------------------------------------------
// 3-layer LSTM encoder. B=64, T=1024, D=512, H=1024. Persistent kernel,
// grid=256 WGs (1/CU), 3 sequential phases. Per phase: fused [Wx;Wh] bf16
// weights live in LDS (K-split 8 x N-split 32). Per time step:
//   GEMM partials (bf16 MFMA 16x16x32, fp32 acc) -> P   | grid barrier
//   gate pass (fp32): c = f*c + i*g, h = o*tanh(c)      | grid barrier
// Workspace: P 8MB + c 256KB + h 128KB + h0 128MB + h1 128MB ~= 277MB.
// ---------------------------------------------------------------------------

typedef __attribute__((ext_vector_type(8))) short short8;
typedef __attribute__((ext_vector_type(4))) float f32x4;

#define GRID   256
#define WGS    256
#define KB     8          // K-split factor
#define NB     32         // N-split factor (n-block = 128)
#define NBLK   128
#define TSTEPS 1024
#define HID    1024
#define BATCH  64
#define ZN     4096
#define LDS_BYTES 90112   // > 64KB (needs attr), forces 1 WG/CU (2*88KB > 160KB)

__device__ __forceinline__ unsigned short f2bf(float f) {
    unsigned u = __float_as_uint(f);
    u += 0x7fffu + ((u >> 16) & 1u);      // round-to-nearest-even
    return (unsigned short)(u >> 16);
}

__device__ __forceinline__ float fast_tanh(float x) {
    x = fminf(15.f, fmaxf(-15.f, x));
    float e = __expf(2.f * x);
    return (e - 1.f) / (e + 1.f);
}

__device__ __forceinline__ float sigm(float x) {
    return 1.f / (1.f + __expf(-x));
}

// Monotone-counter grid barrier. Counter zeroed by init kernel each launch.
__device__ __forceinline__ void gbar(unsigned* cnt, unsigned& tgt) {
    tgt += GRID;
    __threadfence();                       // release: flush stores (agent scope)
    __syncthreads();
    if (threadIdx.x == 0) {
        __hip_atomic_fetch_add(cnt, 1u, __ATOMIC_ACQ_REL, __HIP_MEMORY_SCOPE_AGENT);
        while (__hip_atomic_load(cnt, __ATOMIC_RELAXED, __HIP_MEMORY_SCOPE_AGENT) < tgt)
            __builtin_amdgcn_s_sleep(2);
    }
    __syncthreads();
    (void)__hip_atomic_load(cnt, __ATOMIC_ACQUIRE, __HIP_MEMORY_SCOPE_AGENT);
    __threadfence();                       // acquire: invalidate L1/L2 before reads
}

__global__ void initk(unsigned* barcnt) {
    if (threadIdx.x == 0) *barcnt = 0u;
}

__global__ __launch_bounds__(WGS) void lstm3(
    const float* __restrict__ xs,
    const float* __restrict__ Wx0, const float* __restrict__ Wh0, const float* __restrict__ b0,
    const float* __restrict__ Wx1, const float* __restrict__ Wh1, const float* __restrict__ b1,
    const float* __restrict__ Wx2, const float* __restrict__ Wh2, const float* __restrict__ b2,
    float* __restrict__ out,
    float* __restrict__ P,               // [KB][BATCH][ZN] fp32 partials
    float* __restrict__ cst,             // [BATCH][HID] fp32 cell state
    unsigned short* __restrict__ hst,    // [BATCH][HID] bf16 hidden state
    unsigned short* __restrict__ h0buf,  // [BATCH][TSTEPS][HID] bf16
    unsigned short* __restrict__ h1buf,  // [BATCH][TSTEPS][HID] bf16
    unsigned* __restrict__ barcnt)
{
    extern __shared__ unsigned short WT[];   // weight tile, [n][k] k-contiguous, +8 pad

    const int wg  = blockIdx.x;
    const int tid = threadIdx.x;
    const int nb  = wg & 31;        // n-block id (0..31)
    const int kb  = wg >> 5;        // k-slice id (0..7)
    const int wv   = tid >> 6;
    const int lane = tid & 63;
    const int mh = wv & 1;          // wave m-half (0..1) -> rows mh*32..+31
    const int nh = wv >> 1;         // wave n-half (0..1) -> cols nh*64..+63
    const int l15  = lane & 15;
    const int quad = lane >> 4;

    unsigned btgt = 0;

    for (int phase = 0; phase < 3; ++phase) {
        const float* Wx  = phase == 0 ? Wx0 : (phase == 1 ? Wx1 : Wx2);
        const float* Wh  = phase == 0 ? Wh0 : (phase == 1 ? Wh1 : Wh2);
        const float* bia = phase == 0 ? b0  : (phase == 1 ? b1  : b2);
        const unsigned short* xprev = phase == 1 ? h0buf : (phase == 2 ? h1buf : (unsigned short*)0);
        unsigned short* hout = phase == 0 ? h0buf : (phase == 1 ? h1buf : (unsigned short*)0);
        const int Kx   = (phase == 0) ? 512 : 1024;
        const int ks   = (Kx + HID) / KB;     // k-slice rows: 192 or 256
        const int ldr  = ks + 8;              // padded LDS row (bf16 units)
        const int nkit = ks >> 5;             // 32-k blocks per slice: 6 or 8

        // ---- zero c/h state (each WG zeroes its 256-element slice) ----
        {
            int idx = wg * WGS + tid;         // 0..65535 == BATCH*HID
            cst[idx] = 0.f;
            hst[idx] = (unsigned short)0;
        }

        // ---- fill LDS weight tile (transposed to [n][k]), f32 -> bf16 ----
        for (int kk = (tid >> 7); kk < ks; kk += 2) {
            int nl = tid & 127;
            int gk = kb * ks + kk;
            int gn = nb * NBLK + nl;
            float w = (gk < Kx) ? Wx[(size_t)gk * ZN + gn]
                                : Wh[(size_t)(gk - Kx) * ZN + gn];
            WT[nl * ldr + kk] = f2bf(w);
        }
        gbar(barcnt, btgt);   // states zeroed + LDS filled (LDS is WG-local; barrier covers states)

        // ---- time loop ----
        for (int t = 0; t < TSTEPS; ++t) {
            // ---------- GEMM: WG tile [64m x 128n x ks k]; wave tile [32m x 64n]
            f32x4 acc[2][4];
            #pragma unroll
            for (int a = 0; a < 2; ++a)
                #pragma unroll
                for (int c = 0; c < 4; ++c)
                    acc[a][c] = (f32x4){0.f, 0.f, 0.f, 0.f};

            for (int kit = 0; kit < nkit; ++kit) {
                int kbase = kb * ks + (kit << 5);     // 32-aligned; never straddles Kx
                int ko    = quad << 3;                // lane's 8-elem k offset in block
                bool isx  = (kbase < Kx);

                short8 af[2];
                #pragma unroll
                for (int mt = 0; mt < 2; ++mt) {
                    int m = mh * 32 + mt * 16 + l15;  // batch row 0..63
                    if (isx) {
                        if (phase == 0) {
                            const float* p = xs + (size_t)(m * TSTEPS + t) * 512 + kbase + ko;
                            f32x4 lo = *(const f32x4*)p;
                            f32x4 hi = *(const f32x4*)(p + 4);
                            short8 v;
                            #pragma unroll
                            for (int j = 0; j < 4; ++j) {
                                v[j]     = (short)f2bf(lo[j]);
                                v[j + 4] = (short)f2bf(hi[j]);
                            }
                            af[mt] = v;
                        } else {
                            af[mt] = *(const short8*)(xprev + (size_t)(m * TSTEPS + t) * HID + kbase + ko);
                        }
                    } else {
                        af[mt] = *(const short8*)(hst + (m << 10) + (kbase - Kx + ko));
                    }
                }
                #pragma unroll
                for (int nt = 0; nt < 4; ++nt) {
                    // B-frag: lane holds B[n=l15][k=quad*8+j], k contiguous in LDS
                    short8 bf = *(const short8*)&WT[(nh * 64 + nt * 16 + l15) * ldr + (kit << 5) + ko];
                    acc[0][nt] = __builtin_amdgcn_mfma_f32_16x16x32_bf16(af[0], bf, acc[0][nt], 0, 0, 0);
                    acc[1][nt] = __builtin_amdgcn_mfma_f32_16x16x32_bf16(af[1], bf, acc[1][nt], 0, 0, 0);
                }
            }

            // ---------- store partials: D[m][n], m=(quad*4+reg), n=l15 within tile
            #pragma unroll
            for (int mt = 0; mt < 2; ++mt) {
                #pragma unroll
                for (int nt = 0; nt < 4; ++nt) {
                    int n  = nb * NBLK + nh * 64 + nt * 16 + l15;
                    int mb = mh * 32 + mt * 16 + quad * 4;
                    #pragma unroll
                    for (int r = 0; r < 4; ++r)
                        P[((size_t)(kb * BATCH + mb + r)) * ZN + n] = acc[mt][nt][r];
                }
            }
            gbar(barcnt, btgt);

            // ---------- gate pass: WG handles cols [wg*4, wg*4+4) x all 64 batch
            {
                int bi  = tid >> 2;
                int col = (wg << 2) + (tid & 3);
                float z0 = bia[0 * HID + col];
                float z1 = bia[1 * HID + col];
                float z2 = bia[2 * HID + col];
                float z3 = bia[3 * HID + col];
                #pragma unroll
                for (int k2 = 0; k2 < KB; ++k2) {
                    const float* pr = P + ((size_t)(k2 * BATCH + bi)) * ZN + col;
                    z0 += pr[0 * HID];
                    z1 += pr[1 * HID];
                    z2 += pr[2 * HID];
                    z3 += pr[3 * HID];
                }
                float ig = sigm(z0);
                float fg = sigm(z1);
                float gg = fast_tanh(z2);
                float og = sigm(z3);
                int sidx = (bi << 10) + col;
                float c  = fg * cst[sidx] + ig * gg;
                cst[sidx] = c;
                float h  = og * fast_tanh(c);
                hst[sidx] = f2bf(h);
                if (phase < 2) hout[(size_t)(bi * TSTEPS + t) * HID + col] = f2bf(h);
                else           out[(size_t)(bi * TSTEPS + t) * HID + col]  = h;
            }
            gbar(barcnt, btgt);
        }
    }
}

extern "C" void kernel_launch(void* const* d_in, const int* in_sizes, int n_in,
                              void* d_out, int out_size, void* d_ws, size_t ws_size,
                              hipStream_t stream) {
    const float* xs  = (const float*)d_in[0];
    const float* Wx0 = (const float*)d_in[1];
    const float* Wh0 = (const float*)d_in[2];
    const float* b0  = (const float*)d_in[3];
    const float* Wx1 = (const float*)d_in[4];
    const float* Wh1 = (const float*)d_in[5];
    const float* b1  = (const float*)d_in[6];
    const float* Wx2 = (const float*)d_in[7];
    const float* Wh2 = (const float*)d_in[8];
    const float* b2  = (const float*)d_in[9];

    unsigned char* w = (unsigned char*)d_ws;
    float* P = (float*)w;                 w += (size_t)KB * BATCH * ZN * sizeof(float);   // 8 MB
    float* cstate = (float*)w;            w += (size_t)BATCH * HID * sizeof(float);       // 256 KB
    unsigned short* hstate = (unsigned short*)w; w += (size_t)BATCH * HID * 2;            // 128 KB
    unsigned* barcnt = (unsigned*)w;      w += 256;
    unsigned short* h0 = (unsigned short*)w; w += (size_t)BATCH * TSTEPS * HID * 2;       // 128 MB
    unsigned short* h1 = (unsigned short*)w; w += (size_t)BATCH * TSTEPS * HID * 2;       // 128 MB

    (void)hipFuncSetAttribute((const void*)lstm3,
                              hipFuncAttributeMaxDynamicSharedMemorySize, LDS_BYTES);

    initk<<<1, 64, 0, stream>>>(barcnt);
    lstm3<<<GRID, WGS, LDS_BYTES, stream>>>(
        xs, Wx0, Wh0, b0, Wx1, Wh1, b1, Wx2, Wh2, b2,
        (float*)d_out, P, cstate, hstate, h0, h1, barcnt);
}

// Round 2
// 55758.258 us; speedup vs baseline: 9.7369x; 9.7369x over previous
//
#include <hip/hip_runtime.h>
#include <hip/hip_bf16.h>

// ---------------------------------------------------------------------------
// 3-layer LSTM, B=64, T=1024, D=512, H=1024. Persistent kernel, 256 WGs
// (1/CU), output-column partitioning: WG owns 4 hidden cols => 16 z-cols
// (4 gates x 4) with FULL K. Weights [16][K] bf16 in LDS (~64KB). Per step:
//   each wave: z[16m x 16n] = A[16 x K] * W[K x 16] via 16x16x32 bf16 MFMA
//   z -> LDS, local gate pass (c-state in LDS), h -> MALL via agent-scope
//   atomic stores (packed uint), ONE grid barrier (tid0-gated inv fence).
// No cross-WG reduction, no P buffer. hbufs flushed once per phase (wbl2).
// ---------------------------------------------------------------------------

typedef __attribute__((ext_vector_type(8))) short short8;
typedef __attribute__((ext_vector_type(4))) float f32x4;

#define GRID   256
#define WGS    256
#define TSTEPS 1024
#define HID    1024
#define BATCH  64
#define ZN     4096
#define WTLD   2056              // LDS weight row stride (shorts): 2048 + 8 pad
#define LDS_BYTES 90112          // forces 1 WG/CU; actual use ~71 KB

#define ZL_OFF  65792            // 16*2056*2
#define CS_OFF  (ZL_OFF + 64*17*4)

__device__ __forceinline__ unsigned short f2bf(float f) {
    unsigned u = __float_as_uint(f);
    u += 0x7fffu + ((u >> 16) & 1u);      // round-to-nearest-even
    return (unsigned short)(u >> 16);
}

__device__ __forceinline__ float fast_tanh(float x) {
    x = fminf(15.f, fmaxf(-15.f, x));
    float e = __expf(2.f * x);
    return (e - 1.f) / (e + 1.f);
}

__device__ __forceinline__ float sigm(float x) {
    return 1.f / (1.f + __expf(-x));
}

// Grid barrier. strong=true adds release writeback (wbl2) for plain dirty
// stores (hbuf/out) -- used at phase boundaries only. Per-step barrier needs
// only acquire-inv: h-state travels via MALL-coherent atomic stores, and
// __syncthreads' vmcnt(0) drain orders them before the counter bump.
__device__ __forceinline__ void gbar(unsigned* cnt, unsigned& tgt, bool strong) {
    tgt += GRID;
    __syncthreads();
    if (threadIdx.x == 0) {
        if (strong)
            __builtin_amdgcn_fence(__ATOMIC_RELEASE, "agent");   // wbl2
        __hip_atomic_fetch_add(cnt, 1u, __ATOMIC_RELAXED, __HIP_MEMORY_SCOPE_AGENT);
        while (__hip_atomic_load(cnt, __ATOMIC_RELAXED, __HIP_MEMORY_SCOPE_AGENT) < tgt)
            __builtin_amdgcn_s_sleep(2);
        __builtin_amdgcn_fence(__ATOMIC_ACQUIRE, "agent");       // inv L1+L2
    }
    __syncthreads();
}

__global__ void initk(unsigned* barcnt) {
    if (threadIdx.x == 0) *barcnt = 0u;
}

__global__ __launch_bounds__(WGS) void lstm3(
    const float* __restrict__ xs,
    const float* __restrict__ Wx0, const float* __restrict__ Wh0, const float* __restrict__ b0,
    const float* __restrict__ Wx1, const float* __restrict__ Wh1, const float* __restrict__ b1,
    const float* __restrict__ Wx2, const float* __restrict__ Wh2, const float* __restrict__ b2,
    float* __restrict__ out,
    unsigned* __restrict__ hst32,        // [BATCH][HID/2] packed bf16 pairs (MALL-coherent)
    unsigned short* __restrict__ h0buf,  // [BATCH][TSTEPS][HID] bf16
    unsigned short* __restrict__ h1buf,
    unsigned* __restrict__ barcnt)
{
    extern __shared__ unsigned char lds[];
    unsigned short* WT  = (unsigned short*)lds;            // [16][WTLD] k-contiguous
    float*          zl  = (float*)(lds + ZL_OFF);          // [64][17]
    float*          csl = (float*)(lds + CS_OFF);          // [256] cell state

    const int tid  = threadIdx.x;
    const int wg   = blockIdx.x;
    const int wv   = tid >> 6;
    const int lane = tid & 63;
    const int l15  = lane & 15;
    const int quad = lane >> 4;
    const int am   = (wv << 4) + l15;    // this lane's A (batch) row, 0..63
    const int m_g  = tid >> 2;           // gate-pass batch row
    const int hc   = tid & 3;            // gate-pass hidden col within WG's 4
    const unsigned short* hstU = (const unsigned short*)hst32;  // [64][1024]

    unsigned btgt = 0;

    for (int phase = 0; phase < 3; ++phase) {
        const float* Wx  = phase == 0 ? Wx0 : (phase == 1 ? Wx1 : Wx2);
        const float* Wh  = phase == 0 ? Wh0 : (phase == 1 ? Wh1 : Wh2);
        const float* bia = phase == 0 ? b0  : (phase == 1 ? b1  : b2);
        const unsigned short* xb = phase == 1 ? h0buf : (phase == 2 ? h1buf : (unsigned short*)0);
        unsigned short* ho = phase == 0 ? h0buf : (phase == 1 ? h1buf : (unsigned short*)0);
        const int Kx = (phase == 0) ? 512 : 1024;

        // ---- LDS weight fill: WT[n][k], n -> z-col (gate g = n>>2, col wg*4+(n&3))
        for (int k = tid >> 4; k < Kx + HID; k += 16) {
            int n    = tid & 15;
            int gcol = ((n >> 2) << 10) + (wg << 2) + (n & 3);
            float w  = (k < Kx) ? Wx[(size_t)k * ZN + gcol]
                                : Wh[(size_t)(k - Kx) * ZN + gcol];
            WT[n * WTLD + k] = f2bf(w);
        }
        // ---- zero h-state (packed uints, MALL path) + cell state (LDS)
        if (tid < 128)
            __hip_atomic_store(&hst32[(wg << 7) + tid], 0u,
                               __ATOMIC_RELAXED, __HIP_MEMORY_SCOPE_AGENT);
        csl[tid] = 0.f;
        // ---- per-thread bias registers for the gate pass
        const int gc = (wg << 2) + hc;
        float bi_ = bia[gc], bf_ = bia[HID + gc], bg_ = bia[2 * HID + gc], bo_ = bia[3 * HID + gc];

        gbar(barcnt, btgt, true);   // phase boundary: flush prev phase's ho

        for (int t = 0; t < TSTEPS; ++t) {
            f32x4 acc0 = {0.f,0.f,0.f,0.f}, acc1 = {0.f,0.f,0.f,0.f};
            f32x4 acc2 = {0.f,0.f,0.f,0.f}, acc3 = {0.f,0.f,0.f,0.f};
            const int ko = quad << 3;    // lane k-offset (8 bf16)

            // ---- x segment
            if (phase == 0) {
                const float* xr = xs + ((size_t)am * TSTEPS + t) * 512 + ko;
                #pragma unroll 4
                for (int kit = 0; kit < 16; ++kit) {
                    f32x4 lo = *(const f32x4*)(xr + (kit << 5));
                    f32x4 hi = *(const f32x4*)(xr + (kit << 5) + 4);
                    short8 a;
                    #pragma unroll
                    for (int j = 0; j < 4; ++j) {
                        a[j]     = (short)f2bf(lo[j]);
                        a[j + 4] = (short)f2bf(hi[j]);
                    }
                    short8 b = *(const short8*)&WT[l15 * WTLD + (kit << 5) + ko];
                    switch (kit & 3) {
                        case 0: acc0 = __builtin_amdgcn_mfma_f32_16x16x32_bf16(a, b, acc0, 0, 0, 0); break;
                        case 1: acc1 = __builtin_amdgcn_mfma_f32_16x16x32_bf16(a, b, acc1, 0, 0, 0); break;
                        case 2: acc2 = __builtin_amdgcn_mfma_f32_16x16x32_bf16(a, b, acc2, 0, 0, 0); break;
                        default:acc3 = __builtin_amdgcn_mfma_f32_16x16x32_bf16(a, b, acc3, 0, 0, 0); break;
                    }
                }
            } else {
                const unsigned short* xr = xb + ((size_t)am * TSTEPS + t) * HID + ko;
                #pragma unroll 8
                for (int kit = 0; kit < 32; ++kit) {
                    short8 a = *(const short8*)(xr + (kit << 5));
                    short8 b = *(const short8*)&WT[l15 * WTLD + (kit << 5) + ko];
                    switch (kit & 3) {
                        case 0: acc0 = __builtin_amdgcn_mfma_f32_16x16x32_bf16(a, b, acc0, 0, 0, 0); break;
                        case 1: acc1 = __builtin_amdgcn_mfma_f32_16x16x32_bf16(a, b, acc1, 0, 0, 0); break;
                        case 2: acc2 = __builtin_amdgcn_mfma_f32_16x16x32_bf16(a, b, acc2, 0, 0, 0); break;
                        default:acc3 = __builtin_amdgcn_mfma_f32_16x16x32_bf16(a, b, acc3, 0, 0, 0); break;
                    }
                }
            }
            // ---- h segment (recurrent), K = 1024 from hstU (cached loads)
            {
                const unsigned short* hr = hstU + (am << 10) + ko;
                #pragma unroll 8
                for (int kit = 0; kit < 32; ++kit) {
                    short8 a = *(const short8*)(hr + (kit << 5));
                    short8 b = *(const short8*)&WT[l15 * WTLD + Kx + (kit << 5) + ko];
                    switch (kit & 3) {
                        case 0: acc0 = __builtin_amdgcn_mfma_f32_16x16x32_bf16(a, b, acc0, 0, 0, 0); break;
                        case 1: acc1 = __builtin_amdgcn_mfma_f32_16x16x32_bf16(a, b, acc1, 0, 0, 0); break;
                        case 2: acc2 = __builtin_amdgcn_mfma_f32_16x16x32_bf16(a, b, acc2, 0, 0, 0); break;
                        default:acc3 = __builtin_amdgcn_mfma_f32_16x16x32_bf16(a, b, acc3, 0, 0, 0); break;
                    }
                }
            }
            f32x4 z4 = (acc0 + acc1) + (acc2 + acc3);
            // D-frag: row m = quad*4 + r (within wave's 16), col n = l15
            #pragma unroll
            for (int r = 0; r < 4; ++r)
                zl[((wv << 4) + (quad << 2) + r) * 17 + l15] = z4[r];
            __syncthreads();

            // ---- gate pass: thread = (m_g, hc); z-cols g*4+hc, g = 0..3
            {
                float zi = zl[m_g * 17 + hc]      + bi_;
                float zf = zl[m_g * 17 + 4 + hc]  + bf_;
                float zg = zl[m_g * 17 + 8 + hc]  + bg_;
                float zo = zl[m_g * 17 + 12 + hc] + bo_;
                float ig = sigm(zi), fg = sigm(zf);
                float gg = fast_tanh(zg), og = sigm(zo);
                float c  = fg * csl[tid] + ig * gg;
                csl[tid] = c;
                float h  = og * fast_tanh(c);

                unsigned hb = (unsigned)f2bf(h);
                unsigned ob = (unsigned)__shfl_xor((int)hb, 1);
                if ((tid & 1) == 0) {
                    unsigned packed = hb | (ob << 16);
                    __hip_atomic_store(&hst32[(m_g << 9) + (wg << 1) + (hc >> 1)], packed,
                                       __ATOMIC_RELAXED, __HIP_MEMORY_SCOPE_AGENT);
                    if (phase < 2)
                        *(unsigned*)&ho[((size_t)m_g * TSTEPS + t) * HID + gc] = packed;
                }
                if (phase == 2)
                    out[((size_t)m_g * TSTEPS + t) * HID + gc] = h;
            }
            gbar(barcnt, btgt, false);
        }
    }
}

extern "C" void kernel_launch(void* const* d_in, const int* in_sizes, int n_in,
                              void* d_out, int out_size, void* d_ws, size_t ws_size,
                              hipStream_t stream) {
    const float* xs  = (const float*)d_in[0];
    const float* Wx0 = (const float*)d_in[1];
    const float* Wh0 = (const float*)d_in[2];
    const float* b0  = (const float*)d_in[3];
    const float* Wx1 = (const float*)d_in[4];
    const float* Wh1 = (const float*)d_in[5];
    const float* b1  = (const float*)d_in[6];
    const float* Wx2 = (const float*)d_in[7];
    const float* Wh2 = (const float*)d_in[8];
    const float* b2  = (const float*)d_in[9];

    unsigned char* w = (unsigned char*)d_ws;
    unsigned* barcnt = (unsigned*)w;       w += 256;
    unsigned* hst32  = (unsigned*)w;       w += (size_t)BATCH * (HID / 2) * 4;        // 128 KB
    unsigned short* h0 = (unsigned short*)w; w += (size_t)BATCH * TSTEPS * HID * 2;   // 128 MB
    unsigned short* h1 = (unsigned short*)w; w += (size_t)BATCH * TSTEPS * HID * 2;   // 128 MB

    (void)hipFuncSetAttribute((const void*)lstm3,
                              hipFuncAttributeMaxDynamicSharedMemorySize, LDS_BYTES);

    initk<<<1, 64, 0, stream>>>(barcnt);
    lstm3<<<GRID, WGS, LDS_BYTES, stream>>>(
        xs, Wx0, Wh0, b0, Wx1, Wh1, b1, Wx2, Wh2, b2,
        (float*)d_out, hst32, h0, h1, barcnt);
}